// Round 5
// baseline (272.920 us; speedup 1.0000x reference)
//
#include <hip/hip_runtime.h>
#include <hip/hip_bf16.h>

#define RAG   2048          // BS*NA
#define KP    672           // padded K (real 650): k' = i*64+h for k'<640, aug 640..649
#define QOFF  45056         // 128*16*22

typedef __attribute__((ext_vector_type(8))) short short8;
typedef __attribute__((ext_vector_type(4))) float f32x4;

__device__ inline unsigned short f2bf(float f){
    unsigned u = __float_as_uint(f);
    u += 0x7fffu + ((u >> 16) & 1u);            // RNE
    return (unsigned short)(u >> 16);
}
__device__ inline unsigned pack2(float a, float b){
    return (unsigned)f2bf(a) | ((unsigned)f2bf(b) << 16);
}

// ---------------- K1: blocks 0..2047 = per-agent Usum rows (enemy + ally);
// blocks 2048..2089 = B prepack into K-step-blocked layout B[step][n][32] (coalesced);
// block 2090 = Wgru/B2 prepack. ----------------
__global__ void __launch_bounds__(256) k_usum(
    const float* __restrict__ ef, const float* __restrict__ hew1, const float* __restrict__ heb1,
    const float* __restrict__ af, const float* __restrict__ haw1, const float* __restrict__ hab1,
    const float* __restrict__ hew2, const float* __restrict__ heb2,
    const float* __restrict__ haw2, const float* __restrict__ hab2,
    const float* __restrict__ wih, const float* __restrict__ whh, const float* __restrict__ f2w1,
    unsigned short* __restrict__ Bte, unsigned short* __restrict__ Bta,
    unsigned short* __restrict__ Wgru, unsigned short* __restrict__ B2,
    unsigned short* __restrict__ usum)
{
    int bb = blockIdx.x, tid = threadIdx.x;
    if (bb >= RAG){
        int p = bb - RAG;
        if (p < 42){
            int mat = p & 1;                 // 0 = enemy, 1 = ally
            int s   = p >> 1;                // kstep 0..20
            const float* w2 = mat ? haw2 : hew2;
            const float* b2 = mat ? hab2 : heb2;
            int ld = mat ? 2560 : 2820;
            unsigned short* Bt = mat ? Bta : Bte;
            unsigned pk[16];
#pragma unroll
            for (int j = 0; j < 16; ++j){
                int k0 = s*32 + j*2, k1 = k0 + 1;
                float v0 = 0.f, v1 = 0.f;
                if (k0 < 640)      v0 = w2[(k0 & 63)*ld + (k0 >> 6)*256 + tid];
                else if (k0 < 650) v0 = b2[(k0 - 640)*256 + tid];
                if (k1 < 640)      v1 = w2[(k1 & 63)*ld + (k1 >> 6)*256 + tid];
                else if (k1 < 650) v1 = b2[(k1 - 640)*256 + tid];
                pk[j] = pack2(v0, v1);
            }
            uint4* dst = (uint4*)&Bt[s*8192 + tid*32];
            dst[0] = (uint4){pk[0],  pk[1],  pk[2],  pk[3]};
            dst[1] = (uint4){pk[4],  pk[5],  pk[6],  pk[7]};
            dst[2] = (uint4){pk[8],  pk[9],  pk[10], pk[11]};
            dst[3] = (uint4){pk[12], pk[13], pk[14], pk[15]};
        } else {
            // Wgru [256 cols][128 k] : cols = [r-sum(128) | inn(64, wih only) | hn(64, whh only)]
            for (int it = tid; it < 256*128; it += 256){
                int n = it >> 7, k = it & 127;
                float v;
                if (n < 128)      v = (k < 64) ? wih[n*64 + k] : whh[n*64 + k - 64];
                else if (n < 192) v = (k < 64) ? wih[n*64 + k] : 0.f;
                else              v = (k < 64) ? 0.f : whh[(n-64)*64 + k - 64];
                Wgru[it] = f2bf(v);
            }
            for (int it = tid; it < 64*64; it += 256){
                int n = it >> 6, k = it & 63;
                B2[it] = f2bf(f2w1[k*64 + n]);
            }
        }
        return;
    }
    __shared__ float s_ef[16][10], s_af[15][10];
    __shared__ float s_he[16][64], s_ha[15][64];
    int ag = bb;
    if (tid < 160) s_ef[tid/10][tid%10] = ef[ag*160 + tid];
    if (tid < 150) s_af[tid/10][tid%10] = af[ag*150 + tid];
    __syncthreads();
    for (int idx = tid; idx < 16*64; idx += 256){
        int en = idx >> 6, h = idx & 63;
        float s = heb1[h];
#pragma unroll
        for (int i = 0; i < 10; ++i) s = fmaf(s_ef[en][i], hew1[i*64 + h], s);
        s_he[en][h] = fmaxf(s, 0.f);
    }
    for (int idx = tid; idx < 15*64; idx += 256){
        int l = idx >> 6, h = idx & 63;
        float s = hab1[h];
#pragma unroll
        for (int i = 0; i < 10; ++i) s = fmaf(s_af[l][i], haw1[i*64 + h], s);
        s_ha[l][h] = fmaxf(s, 0.f);
    }
    __syncthreads();
    for (int k = tid; k < KP; k += 256){
        float ue = 0.f, ua = 0.f;
        if (k < 640){
            int i = k >> 6, h = k & 63;
#pragma unroll
            for (int en = 0; en < 16; ++en) ue = fmaf(s_he[en][h], s_ef[en][i], ue);
#pragma unroll
            for (int l = 0; l < 15; ++l) ua = fmaf(s_ha[l][h], s_af[l][i], ua);
        } else if (k < 650){
            int i = k - 640;
#pragma unroll
            for (int en = 0; en < 16; ++en) ue += s_ef[en][i];
#pragma unroll
            for (int l = 0; l < 15; ++l) ua += s_af[l][i];
        }
        usum[ag*KP + k]         = f2bf(ue);
        usum[(RAG + ag)*KP + k] = f2bf(ua);
    }
}

// Coalesced B-tile staging: step-tile is contiguous 16KB; thread tid loads 4x16B at
// stride 4KB; LDS rows padded to 36 ushorts (conflict-free fragment reads).
#define STAGE_B(Bbase, s)                                                        \
    const unsigned short* Bs = (Bbase) + (s)*8192;                               \
    uint4 bq0 = *(const uint4*)&Bs[tid*8 + 0*2048];                              \
    uint4 bq1 = *(const uint4*)&Bs[tid*8 + 1*2048];                              \
    uint4 bq2 = *(const uint4*)&Bs[tid*8 + 2*2048];                              \
    uint4 bq3 = *(const uint4*)&Bs[tid*8 + 3*2048];

#define WRITE_B()                                                                \
    *(uint4*)&sB[nb + 0*2304] = bq0;                                             \
    *(uint4*)&sB[nb + 1*2304] = bq1;                                             \
    *(uint4*)&sB[nb + 2*2304] = bq2;                                             \
    *(uint4*)&sB[nb + 3*2304] = bq3;

// ---------------- K2: MFMA GEMMs. blocks 0..479: ally rows (A generated on-the-fly,
// passing-MLP epilogue). blocks 480..543: one stacked-usum tile each -> emb. ----------------
__global__ void __launch_bounds__(256, 3) k_gemm(
    const unsigned short* __restrict__ Bte, const unsigned short* __restrict__ Bta,
    const float* __restrict__ haw1, const float* __restrict__ hab1,
    const float* __restrict__ af, const unsigned short* __restrict__ usum,
    const float* __restrict__ pw1, const float* __restrict__ pb1,
    const float* __restrict__ pw2, const float* __restrict__ pb2,
    float* __restrict__ emb, float* __restrict__ p2)
{
    __shared__ __align__(16) char smem[46080];
    unsigned short* sB  = (unsigned short*)smem;            // [256][36] bf16 = 18432 B
    unsigned short* sA  = (unsigned short*)(smem + 18432);  // [64][40]  = 5120 B
    unsigned short* sW1 = (unsigned short*)(smem + 36864);  // [64][72B] pw1^T = 9216 B

    int tid = threadIdx.x;
    int w = tid >> 6;
    int lane = tid & 63;
    int l15 = lane & 15, quad = lane >> 4;
    int bb = blockIdx.x;
    int nb = (tid >> 2)*36 + (tid & 3)*8;   // LDS ushort offset for B staging writes

    f32x4 acc[4][4];
#pragma unroll
    for (int a = 0; a < 4; ++a)
#pragma unroll
    for (int b = 0; b < 4; ++b) acc[a][b] = (f32x4){0.f, 0.f, 0.f, 0.f};

    if (bb < 480){
        int row0 = bb * 64;
        int r = tid >> 2, c = tid & 3;
#pragma unroll
        for (int p = 0; p < 16; ++p){
            int idx = tid + p*256;
            sW1[(idx & 63)*36 + (idx >> 6)] = f2bf(pw1[idx]);
        }
        float af_reg[10];
        {
            const float* ap = af + (row0 + r)*10;
#pragma unroll
            for (int i = 0; i < 10; ++i) af_reg[i] = ap[i];
        }
        // recompute ally hypernet h1 for this row: the 16 h-values this thread packs
        float h1f[16];
#pragma unroll
        for (int q = 0; q < 8; ++q){
            int h0 = c*8 + q, h1 = 32 + c*8 + q;
            float v0 = hab1[h0], v1 = hab1[h1];
#pragma unroll
            for (int i = 0; i < 10; ++i){
                v0 = fmaf(af_reg[i], haw1[i*64 + h0], v0);
                v1 = fmaf(af_reg[i], haw1[i*64 + h1], v1);
            }
            h1f[q]     = fmaxf(v0, 0.f);
            h1f[8 + q] = fmaxf(v1, 0.f);
        }
#pragma unroll
        for (int i = 0; i < 10; ++i){
#pragma unroll
            for (int hb = 0; hb < 2; ++hb){
                int s = i*2 + hb;
                __syncthreads();
                STAGE_B(Bta, s)
                float avf = af_reg[i];
                uint4 pk;
                pk.x = pack2(h1f[hb*8+0]*avf, h1f[hb*8+1]*avf);
                pk.y = pack2(h1f[hb*8+2]*avf, h1f[hb*8+3]*avf);
                pk.z = pack2(h1f[hb*8+4]*avf, h1f[hb*8+5]*avf);
                pk.w = pack2(h1f[hb*8+6]*avf, h1f[hb*8+7]*avf);
                *(uint4*)&sA[r*40 + c*8] = pk;
                WRITE_B()
                __syncthreads();
                short8 a_[4], b_[4];
#pragma unroll
                for (int mt = 0; mt < 4; ++mt) a_[mt] = *(const short8*)&sA[(mt*16 + l15)*40 + quad*8];
#pragma unroll
                for (int nt = 0; nt < 4; ++nt) b_[nt] = *(const short8*)&sB[(w*64 + nt*16 + l15)*36 + quad*8];
#pragma unroll
                for (int mt = 0; mt < 4; ++mt)
#pragma unroll
                for (int nt = 0; nt < 4; ++nt)
                    acc[mt][nt] = __builtin_amdgcn_mfma_f32_16x16x32_bf16(a_[mt], b_[nt], acc[mt][nt], 0, 0, 0);
            }
        }
        {   // tail kstep s=20: aug rows 640..649 (A = af[i]), 650..671 zero
            __syncthreads();
            STAGE_B(Bta, 20)
            float v0=0.f,v1=0.f,v2=0.f,v3=0.f,v4=0.f,v5=0.f,v6=0.f,v7=0.f;
            if (c == 0){ v0=af_reg[0]; v1=af_reg[1]; v2=af_reg[2]; v3=af_reg[3];
                         v4=af_reg[4]; v5=af_reg[5]; v6=af_reg[6]; v7=af_reg[7]; }
            else if (c == 1){ v0 = af_reg[8]; v1 = af_reg[9]; }
            uint4 pk;
            pk.x = pack2(v0, v1); pk.y = pack2(v2, v3);
            pk.z = pack2(v4, v5); pk.w = pack2(v6, v7);
            *(uint4*)&sA[r*40 + c*8] = pk;
            WRITE_B()
            __syncthreads();
            short8 a_[4], b_[4];
#pragma unroll
            for (int mt = 0; mt < 4; ++mt) a_[mt] = *(const short8*)&sA[(mt*16 + l15)*40 + quad*8];
#pragma unroll
            for (int nt = 0; nt < 4; ++nt) b_[nt] = *(const short8*)&sB[(w*64 + nt*16 + l15)*36 + quad*8];
#pragma unroll
            for (int mt = 0; mt < 4; ++mt)
#pragma unroll
            for (int nt = 0; nt < 4; ++nt)
                acc[mt][nt] = __builtin_amdgcn_mfma_f32_16x16x32_bf16(a_[mt], b_[nt], acc[mt][nt], 0, 0, 0);
        }
        // ---- fused passing-MLP epilogue: wave w == head d ----
        __syncthreads();
        unsigned short* sE = (unsigned short*)(smem + w*9216); // [64][72B] bf16
#pragma unroll
        for (int mt = 0; mt < 4; ++mt)
#pragma unroll
        for (int nt = 0; nt < 4; ++nt)
#pragma unroll
        for (int rg = 0; rg < 4; ++rg)
            sE[(mt*16 + quad*4 + rg)*36 + nt*16 + l15] = f2bf(acc[mt][nt][rg]);
        __syncthreads();
        f32x4 yacc[4][4];
#pragma unroll
        for (int a = 0; a < 4; ++a)
#pragma unroll
        for (int b = 0; b < 4; ++b) yacc[a][b] = (f32x4){0.f, 0.f, 0.f, 0.f};
#pragma unroll
        for (int kb = 0; kb < 2; ++kb){
            short8 ea[4], wb[4];
#pragma unroll
            for (int mt = 0; mt < 4; ++mt) ea[mt] = *(const short8*)&sE[(mt*16 + l15)*36 + kb*16 + quad*8];
#pragma unroll
            for (int ot = 0; ot < 4; ++ot) wb[ot] = *(const short8*)&sW1[(ot*16 + l15)*36 + kb*16 + quad*8];
#pragma unroll
            for (int mt = 0; mt < 4; ++mt)
#pragma unroll
            for (int ot = 0; ot < 4; ++ot)
                yacc[mt][ot] = __builtin_amdgcn_mfma_f32_16x16x32_bf16(ea[mt], wb[ot], yacc[mt][ot], 0, 0, 0);
        }
        float pb1v[4], w2r[4][3];
#pragma unroll
        for (int ot = 0; ot < 4; ++ot){
            pb1v[ot] = pb1[ot*16 + l15];
#pragma unroll
            for (int j = 0; j < 3; ++j) w2r[ot][j] = pw2[(ot*16 + l15)*3 + j];
        }
#pragma unroll
        for (int mt = 0; mt < 4; ++mt){
            float part[4][3];
#pragma unroll
            for (int rg = 0; rg < 4; ++rg)
#pragma unroll
            for (int j = 0; j < 3; ++j) part[rg][j] = 0.f;
#pragma unroll
            for (int ot = 0; ot < 4; ++ot)
#pragma unroll
            for (int rg = 0; rg < 4; ++rg){
                float yv = fmaxf(yacc[mt][ot][rg] + pb1v[ot], 0.f);
#pragma unroll
                for (int j = 0; j < 3; ++j) part[rg][j] = fmaf(yv, w2r[ot][j], part[rg][j]);
            }
#pragma unroll
            for (int off = 1; off < 16; off <<= 1)
#pragma unroll
            for (int rg = 0; rg < 4; ++rg)
#pragma unroll
            for (int j = 0; j < 3; ++j) part[rg][j] += __shfl_xor(part[rg][j], off, 64);
            if (l15 == 0){
#pragma unroll
                for (int rg = 0; rg < 4; ++rg)
#pragma unroll
                for (int j = 0; j < 3; ++j)
                    p2[(row0 + mt*16 + quad*4 + rg)*12 + w*3 + j] = part[rg][j] + pb2[j];
            }
        }
    } else {
        // ---- small GEMM: stacked usum [4096][672] @ Bt -> emb [4096][256] fp32 ----
        int row0 = (bb - 480) * 64;
        const unsigned short* Bbase = (row0 < RAG) ? Bte : Bta;
        const unsigned short* Ab = usum + (row0 + (tid >> 2))*KP + (tid & 3)*8;
        int r = tid >> 2, c = tid & 3;
        for (int s = 0; s < 21; ++s){
            __syncthreads();
            STAGE_B(Bbase, s)
            uint4 aq = *(const uint4*)&Ab[s*32];
            *(uint4*)&sA[r*40 + c*8] = aq;
            WRITE_B()
            __syncthreads();
            short8 a_[4], b_[4];
#pragma unroll
            for (int mt = 0; mt < 4; ++mt) a_[mt] = *(const short8*)&sA[(mt*16 + l15)*40 + quad*8];
#pragma unroll
            for (int nt = 0; nt < 4; ++nt) b_[nt] = *(const short8*)&sB[(w*64 + nt*16 + l15)*36 + quad*8];
#pragma unroll
            for (int mt = 0; mt < 4; ++mt)
#pragma unroll
            for (int nt = 0; nt < 4; ++nt)
                acc[mt][nt] = __builtin_amdgcn_mfma_f32_16x16x32_bf16(a_[mt], b_[nt], acc[mt][nt], 0, 0, 0);
        }
#pragma unroll
        for (int mt = 0; mt < 4; ++mt)
#pragma unroll
        for (int nt = 0; nt < 4; ++nt)
#pragma unroll
        for (int rg = 0; rg < 4; ++rg)
            emb[(row0 + mt*16 + quad*4 + rg)*256 + w*64 + nt*16 + l15] = acc[mt][nt][rg];
    }
}

// ---------------- K3: merge + GRU (MFMA) + heads, 16 agents per block ----------------
__global__ void __launch_bounds__(256) k_final(
    const float* __restrict__ own, const float* __restrict__ hidden,
    const float* __restrict__ fc1w, const float* __restrict__ fc1b,
    const float* __restrict__ mergw,
    const float* __restrict__ bih, const float* __restrict__ bhh,
    const float* __restrict__ f2b1, const float* __restrict__ f2w2, const float* __restrict__ f2b2,
    const unsigned short* __restrict__ Wgru, const unsigned short* __restrict__ B2,
    const float* __restrict__ emb, const float* __restrict__ p2,
    float* __restrict__ out)
{
    __shared__ __align__(16) unsigned short sA16[16*128];   // [agent][x(64)|h(64)] bf16
    __shared__ float sHin[16*65];                           // h_in fp32 (padded)
    __shared__ float sG[256*17];                            // gate pre-acts [col][agent]
    __shared__ float sH2f[16*65];                           // h' fp32
    __shared__ __align__(16) unsigned short sH2b[16*64];    // h' bf16
    __shared__ float sY[16*68];                             // fc2 hidden

    int tid = threadIdx.x;
    int w = tid >> 6, lane = tid & 63;
    int l15 = lane & 15, quad = lane >> 4;
    int ag0 = blockIdx.x * 16;

    // phase 0: x = relu(fc1(own) + merged), stage [x|h] bf16 + h_in fp32
#pragma unroll
    for (int p = 0; p < 4; ++p){
        int idx = tid + p*256;
        int h = idx & 63, a = idx >> 6;
        int ag = ag0 + a;
        float s = fc1b[h];
        const float* ow = own + ag*30;
#pragma unroll
        for (int c = 0; c < 30; ++c) s = fmaf(ow[c], fc1w[c*64 + h], s);
        float m0 = mergw[h], m1 = mergw[64+h], m2 = mergw[128+h], m3 = mergw[192+h];
        float mx = fmaxf(fmaxf(m0, m1), fmaxf(m2, m3));
        float e0 = __expf(m0-mx), e1 = __expf(m1-mx), e2 = __expf(m2-mx), e3 = __expf(m3-mx);
        float inv = 1.f / (e0+e1+e2+e3);
        const float* een = emb + ag*256;
        const float* eal = emb + (RAG + ag)*256;
        float mg = (e0*(een[h]+eal[h]) + e1*(een[64+h]+eal[64+h]) +
                    e2*(een[128+h]+eal[128+h]) + e3*(een[192+h]+eal[192+h])) * inv;
        float x = fmaxf(s + mg, 0.f);
        float hin = hidden[ag*64 + h];
        sA16[a*128 + h]      = f2bf(x);
        sA16[a*128 + 64 + h] = f2bf(hin);
        sHin[a*65 + h] = hin;
    }
    __syncthreads();

    // phase 1: GRU gate GEMM  [16 x 128] @ [128 x 256] -> sG
    {
        f32x4 g_[4];
#pragma unroll
        for (int t = 0; t < 4; ++t) g_[t] = (f32x4){0.f,0.f,0.f,0.f};
#pragma unroll
        for (int ks = 0; ks < 4; ++ks){
            int kt = ks*32;
            short8 a8 = *(const short8*)&sA16[l15*128 + kt + quad*8];
#pragma unroll
            for (int t = 0; t < 4; ++t){
                int col = (w*4 + t)*16 + l15;
                short8 b8 = *(const short8*)&Wgru[col*128 + kt + quad*8];
                g_[t] = __builtin_amdgcn_mfma_f32_16x16x32_bf16(a8, b8, g_[t], 0, 0, 0);
            }
        }
#pragma unroll
        for (int t = 0; t < 4; ++t){
            int col = (w*4 + t)*16 + l15;
#pragma unroll
            for (int rg = 0; rg < 4; ++rg) sG[col*17 + quad*4 + rg] = g_[t][rg];
        }
    }
    __syncthreads();

    // phase 2: gate math -> h'
#pragma unroll
    for (int p = 0; p < 4; ++p){
        int idx = tid + p*256;
        int a = idx & 15, h = idx >> 4;
        float rs  = sG[h*17 + a]        + bih[h]      + bhh[h];
        float zs  = sG[(64+h)*17 + a]   + bih[64+h]   + bhh[64+h];
        float in_ = sG[(128+h)*17 + a]  + bih[128+h];
        float hn  = sG[(192+h)*17 + a]  + bhh[128+h];
        float r = 1.f / (1.f + __expf(-rs));
        float z = 1.f / (1.f + __expf(-zs));
        float n = tanhf(in_ + r*hn);
        float hv = (1.f - z)*n + z*sHin[a*65 + h];
        sH2f[a*65 + h] = hv;
        sH2b[a*64 + h] = f2bf(hv);
    }
    __syncthreads();

    // phase 3: fc2 layer-1 GEMM [16 x 64] @ [64 x 64] -> relu -> sY
    {
        f32x4 y = (f32x4){0.f,0.f,0.f,0.f};
#pragma unroll
        for (int ks = 0; ks < 2; ++ks){
            int kt = ks*32;
            short8 a8 = *(const short8*)&sH2b[l15*64 + kt + quad*8];
            short8 b8 = *(const short8*)&B2[(w*16 + l15)*64 + kt + quad*8];
            y = __builtin_amdgcn_mfma_f32_16x16x32_bf16(a8, b8, y, 0, 0, 0);
        }
        float b1v = f2b1[w*16 + l15];
#pragma unroll
        for (int rg = 0; rg < 4; ++rg)
            sY[(quad*4 + rg)*68 + w*16 + l15] = fmaxf(y[rg] + b1v, 0.f);
    }
    __syncthreads();

    // phase 4: q = y @ f2w2 + b ; passing head ; outputs
    for (int idx = tid; idx < 16*19; idx += 256){
        int a = idx / 19, j = idx - a*19;
        float s2 = f2b2[j];
        for (int c = 0; c < 64; ++c) s2 = fmaf(sY[a*68 + c], f2w2[c*19 + j], s2);
        out[(ag0 + a)*22 + ((j < 9) ? j : j + 3)] = s2;
    }
    if (tid < 48){
        int a = tid / 3, j = tid - a*3;
        float best = -1e30f;
        const float* pp = p2 + (ag0 + a)*180;
        for (int l = 0; l < 15; ++l){
            float mean = 0.25f*(pp[l*12 + j] + pp[l*12 + 3 + j] + pp[l*12 + 6 + j] + pp[l*12 + 9 + j]);
            best = fmaxf(best, mean);
        }
        out[(ag0 + a)*22 + 9 + j] = best;
    }
#pragma unroll
    for (int p = 0; p < 4; ++p){
        int idx = tid + p*256;
        int h = idx & 63, a = idx >> 6;
        out[QOFF + (ag0 + a)*64 + h] = sH2f[a*65 + h];
    }
}

extern "C" void kernel_launch(void* const* d_in, const int* in_sizes, int n_in,
                              void* d_out, int out_size, void* d_ws, size_t ws_size,
                              hipStream_t stream) {
    const float* own    = (const float*)d_in[1];
    const float* allyf  = (const float*)d_in[2];
    const float* enemyf = (const float*)d_in[3];
    const float* hidden = (const float*)d_in[4];
    const float* fc1w   = (const float*)d_in[5];
    const float* fc1b   = (const float*)d_in[6];
    const float* hew1   = (const float*)d_in[7];
    const float* heb1   = (const float*)d_in[8];
    const float* hew2   = (const float*)d_in[9];
    const float* heb2   = (const float*)d_in[10];
    const float* haw1   = (const float*)d_in[11];
    const float* hab1   = (const float*)d_in[12];
    const float* haw2   = (const float*)d_in[13];
    const float* hab2   = (const float*)d_in[14];
    const float* mergw  = (const float*)d_in[15];
    const float* wih    = (const float*)d_in[16];
    const float* whh    = (const float*)d_in[17];
    const float* bih    = (const float*)d_in[18];
    const float* bhh    = (const float*)d_in[19];
    const float* f2w1   = (const float*)d_in[20];
    const float* f2b1   = (const float*)d_in[21];
    const float* f2w2   = (const float*)d_in[22];
    const float* f2b2   = (const float*)d_in[23];
    const float* pw1    = (const float*)d_in[24];
    const float* pb1    = (const float*)d_in[25];
    const float* pw2    = (const float*)d_in[26];
    const float* pb2    = (const float*)d_in[27];
    float* out = (float*)d_out;

    char* W = (char*)d_ws;
    unsigned short* Bte  = (unsigned short*)(W + 0);         // 21*8192*2   = 344064 (blocked)
    unsigned short* Bta  = (unsigned short*)(W + 344064);    // 344064 (blocked)
    unsigned short* usum = (unsigned short*)(W + 688128);    // 4096*672*2  = 5505024
    float*          emb  = (float*)(W + 6193152);            // 4096*256*4  = 4194304
    float*          p2   = (float*)(W + 10387456);           // 30720*12*4  = 1474560
    unsigned short* Wgru = (unsigned short*)(W + 11862016);  // 256*128*2   = 65536
    unsigned short* B2   = (unsigned short*)(W + 11927552);  // 64*64*2     = 8192

    k_usum<<<RAG + 43, 256, 0, stream>>>(enemyf, hew1, heb1, allyf, haw1, hab1,
                                         hew2, heb2, haw2, hab2, wih, whh, f2w1,
                                         Bte, Bta, Wgru, B2, usum);
    k_gemm<<<544, 256, 0, stream>>>(Bte, Bta, haw1, hab1, allyf, usum,
                                    pw1, pb1, pw2, pb2, emb, p2);
    k_final<<<RAG/16, 256, 0, stream>>>(own, hidden, fc1w, fc1b, mergw,
                                        bih, bhh, f2b1, f2w2, f2b2,
                                        Wgru, B2, emb, p2, out);
}

// Round 6
// 224.225 us; speedup vs baseline: 1.2172x; 1.2172x over previous
//
#include <hip/hip_runtime.h>
#include <hip/hip_bf16.h>

#define RAG   2048          // BS*NA
#define KP2   704           // padded K: k' = i*64+h (i<10), aug 640..649, zero 650..703
#define QOFF  45056         // 128*16*22

typedef __attribute__((ext_vector_type(8))) short short8;
typedef __attribute__((ext_vector_type(4))) float f32x4;

__device__ inline unsigned short f2bf(float f){
    unsigned u = __float_as_uint(f);
    u += 0x7fffu + ((u >> 16) & 1u);            // RNE
    return (unsigned short)(u >> 16);
}
__device__ inline unsigned pack2(float a, float b){
    return (unsigned)f2bf(a) | ((unsigned)f2bf(b) << 16);
}
__device__ inline void gload_lds(const void* g, void* l){
    __builtin_amdgcn_global_load_lds(
        (const __attribute__((address_space(1))) void*)g,
        (__attribute__((address_space(3))) void*)l, 16, 0, 0);
}

// ---------------- K1: blocks 0..2047 = per-agent Usum rows (enemy + ally) + ha1;
// blocks 2048..2069 = B prepack (LDS-image swizzled layout); block 2070 = Wgru/B2. ----------------
__global__ void __launch_bounds__(256) k_usum(
    const float* __restrict__ ef, const float* __restrict__ hew1, const float* __restrict__ heb1,
    const float* __restrict__ af, const float* __restrict__ haw1, const float* __restrict__ hab1,
    const float* __restrict__ hew2, const float* __restrict__ heb2,
    const float* __restrict__ haw2, const float* __restrict__ hab2,
    const float* __restrict__ wih, const float* __restrict__ whh, const float* __restrict__ f2w1,
    unsigned short* __restrict__ Bte, unsigned short* __restrict__ Bta,
    unsigned short* __restrict__ Wgru, unsigned short* __restrict__ B2,
    unsigned short* __restrict__ ha1, unsigned short* __restrict__ usum)
{
    int bb = blockIdx.x, tid = threadIdx.x;
    if (bb >= RAG){
        int p = bb - RAG;
        if (p < 22){
            int mat = p & 1;                 // 0 = enemy, 1 = ally
            int s   = p >> 1;                // step 0..10
            const float* w2 = mat ? haw2 : hew2;
            const float* b2 = mat ? hab2 : heb2;
            int ld = mat ? 2560 : 2820;
            unsigned short* Bt = mat ? Bta : Bte;
            int n = tid, n7 = n & 7;
            unsigned pk[32];
#pragma unroll
            for (int u2 = 0; u2 < 32; ++u2){
                int cst = u2 >> 2;                   // stored chunk 0..7
                int co  = cst ^ n7;                  // original chunk
                int j0  = (u2 * 2) & 7;
                int k0 = s*64 + co*8 + j0, k1 = k0 + 1;
                float v0 = 0.f, v1 = 0.f;
                if (k0 < 640)      v0 = w2[(k0 & 63)*ld + (k0 >> 6)*256 + n];
                else if (k0 < 650) v0 = b2[(k0 - 640)*256 + n];
                if (k1 < 640)      v1 = w2[(k1 & 63)*ld + (k1 >> 6)*256 + n];
                else if (k1 < 650) v1 = b2[(k1 - 640)*256 + n];
                pk[u2] = pack2(v0, v1);
            }
            uint4* dst = (uint4*)&Bt[s*16384 + n*64];
#pragma unroll
            for (int q = 0; q < 8; ++q)
                dst[q] = (uint4){pk[q*4], pk[q*4+1], pk[q*4+2], pk[q*4+3]};
        } else {
            for (int it = tid; it < 256*128; it += 256){
                int n = it >> 7, k = it & 127;
                float v;
                if (n < 128)      v = (k < 64) ? wih[n*64 + k] : whh[n*64 + k - 64];
                else if (n < 192) v = (k < 64) ? wih[n*64 + k] : 0.f;
                else              v = (k < 64) ? 0.f : whh[(n-64)*64 + k - 64];
                Wgru[it] = f2bf(v);
            }
            for (int it = tid; it < 64*64; it += 256){
                int n = it >> 6, k = it & 63;
                B2[it] = f2bf(f2w1[k*64 + n]);
            }
        }
        return;
    }
    __shared__ float s_ef[16][10], s_af[15][10];
    __shared__ float s_he[16][64], s_ha[15][64];
    int ag = bb;
    if (tid < 160) s_ef[tid/10][tid%10] = ef[ag*160 + tid];
    if (tid < 150) s_af[tid/10][tid%10] = af[ag*150 + tid];
    __syncthreads();
    for (int idx = tid; idx < 16*64; idx += 256){
        int en = idx >> 6, h = idx & 63;
        float s = heb1[h];
#pragma unroll
        for (int i = 0; i < 10; ++i) s = fmaf(s_ef[en][i], hew1[i*64 + h], s);
        s_he[en][h] = fmaxf(s, 0.f);
    }
    for (int idx = tid; idx < 15*64; idx += 256){
        int l = idx >> 6, h = idx & 63;
        float s = hab1[h];
#pragma unroll
        for (int i = 0; i < 10; ++i) s = fmaf(s_af[l][i], haw1[i*64 + h], s);
        s_ha[l][h] = fmaxf(s, 0.f);
    }
    __syncthreads();
    for (int idx = tid; idx < 15*64; idx += 256){
        int l = idx >> 6, h = idx & 63;
        ha1[(ag*15 + l)*64 + h] = f2bf(s_ha[l][h]);
    }
    for (int k = tid; k < KP2; k += 256){
        float ue = 0.f, ua = 0.f;
        if (k < 640){
            int i = k >> 6, h = k & 63;
#pragma unroll
            for (int en = 0; en < 16; ++en) ue = fmaf(s_he[en][h], s_ef[en][i], ue);
#pragma unroll
            for (int l = 0; l < 15; ++l) ua = fmaf(s_ha[l][h], s_af[l][i], ua);
        } else if (k < 650){
            int i = k - 640;
#pragma unroll
            for (int en = 0; en < 16; ++en) ue += s_ef[en][i];
#pragma unroll
            for (int l = 0; l < 15; ++l) ua += s_af[l][i];
        }
        usum[ag*KP2 + k]         = f2bf(ue);
        usum[(RAG + ag)*KP2 + k] = f2bf(ua);
    }
}

// One MFMA K-step (BK=64), fragments from XOR-swizzled LDS (conflict-free).
#define MFMA_STEP()                                                              \
    _Pragma("unroll")                                                            \
    for (int kk = 0; kk < 2; ++kk){                                              \
        int ch = ((kk*4 + quad) ^ l7) * 8;                                       \
        short8 a_[4], b_[4];                                                     \
        _Pragma("unroll")                                                        \
        for (int mt = 0; mt < 4; ++mt) a_[mt] = *(const short8*)&sA[(mt*16 + l15)*64 + ch]; \
        _Pragma("unroll")                                                        \
        for (int nt = 0; nt < 4; ++nt) b_[nt] = *(const short8*)&sB[(w*64 + nt*16 + l15)*64 + ch]; \
        _Pragma("unroll")                                                        \
        for (int mt = 0; mt < 4; ++mt)                                           \
        _Pragma("unroll")                                                        \
        for (int nt = 0; nt < 4; ++nt)                                           \
            acc[mt][nt] = __builtin_amdgcn_mfma_f32_16x16x32_bf16(a_[mt], b_[nt], acc[mt][nt], 0, 0, 0); \
    }

// ---------------- K2: MFMA GEMMs. blocks 0..479: ally rows (A on-the-fly, passing-MLP
// epilogue). blocks 480..543: stacked usum tiles -> emb (A via global_load_lds). ----------------
__global__ void __launch_bounds__(256, 2) k_gemm(
    const unsigned short* __restrict__ Bte, const unsigned short* __restrict__ Bta,
    const unsigned short* __restrict__ ha1, const float* __restrict__ af,
    const unsigned short* __restrict__ usum,
    const float* __restrict__ pw1, const float* __restrict__ pb1,
    const float* __restrict__ pw2, const float* __restrict__ pb2,
    float* __restrict__ emb, float* __restrict__ p2)
{
    __shared__ __align__(16) char smem[50176];
    unsigned short* sB  = (unsigned short*)smem;            // 256 cols x 64 ushorts, swizzled (32KB)
    unsigned short* sA  = (unsigned short*)(smem + 32768);  // 64 rows x 64 ushorts, swizzled (8KB)
    unsigned short* sW1 = (unsigned short*)(smem + 40960);  // [64][72] pw1^T (9216B)

    int tid = threadIdx.x;
    int w = tid >> 6, lane = tid & 63;
    int l15 = lane & 15, quad = lane >> 4, l7 = l15 & 7;
    int bb = blockIdx.x;

    f32x4 acc[4][4];
#pragma unroll
    for (int a = 0; a < 4; ++a)
#pragma unroll
    for (int b = 0; b < 4; ++b) acc[a][b] = (f32x4){0.f, 0.f, 0.f, 0.f};

    if (bb < 480){
        int row0 = bb * 64;
        int r = tid >> 2, c4 = tid & 3, r7 = r & 7;
#pragma unroll
        for (int p = 0; p < 16; ++p){
            int idx = tid + p*256;
            sW1[(idx & 63)*72 + (idx >> 6)] = f2bf(pw1[idx]);
        }
        float af_reg[10];
        {
            const float* ap = af + (row0 + r)*10;
#pragma unroll
            for (int i = 0; i < 10; ++i) af_reg[i] = ap[i];
        }
        float h1f[16];
        {
            const unsigned short* hp = ha1 + (size_t)(row0 + r)*64 + c4*16;
            uint4 ra = *(const uint4*)hp;
            uint4 rb = *(const uint4*)(hp + 8);
            unsigned va[4] = {ra.x, ra.y, ra.z, ra.w};
            unsigned vb[4] = {rb.x, rb.y, rb.z, rb.w};
#pragma unroll
            for (int q = 0; q < 4; ++q){
                h1f[q*2+0]   = __uint_as_float(va[q] << 16);
                h1f[q*2+1]   = __uint_as_float(va[q] & 0xffff0000u);
                h1f[8+q*2+0] = __uint_as_float(vb[q] << 16);
                h1f[8+q*2+1] = __uint_as_float(vb[q] & 0xffff0000u);
            }
        }
        unsigned short* sAw0 = &sA[r*64 + (((2*c4)     ^ r7) * 8)];
        unsigned short* sAw1 = &sA[r*64 + (((2*c4 + 1) ^ r7) * 8)];
        const char* Bb = (const char*)Bta;
#pragma unroll
        for (int s = 0; s < 10; ++s){
            __syncthreads();
            const char* Bstep = Bb + s*32768;
#pragma unroll
            for (int ii = 0; ii < 8; ++ii)
                gload_lds(Bstep + w*8192 + ii*1024 + lane*16, smem + w*8192 + ii*1024);
            float avf = af_reg[s];
            uint4 p0, p1;
            p0.x = pack2(h1f[0]*avf,  h1f[1]*avf);  p0.y = pack2(h1f[2]*avf,  h1f[3]*avf);
            p0.z = pack2(h1f[4]*avf,  h1f[5]*avf);  p0.w = pack2(h1f[6]*avf,  h1f[7]*avf);
            p1.x = pack2(h1f[8]*avf,  h1f[9]*avf);  p1.y = pack2(h1f[10]*avf, h1f[11]*avf);
            p1.z = pack2(h1f[12]*avf, h1f[13]*avf); p1.w = pack2(h1f[14]*avf, h1f[15]*avf);
            *(uint4*)sAw0 = p0;
            *(uint4*)sAw1 = p1;
            __syncthreads();
            MFMA_STEP()
        }
        {   // tail step s=10: k 640..649 = af[i], rest zero
            __syncthreads();
            const char* Bstep = Bb + 10*32768;
#pragma unroll
            for (int ii = 0; ii < 8; ++ii)
                gload_lds(Bstep + w*8192 + ii*1024 + lane*16, smem + w*8192 + ii*1024);
            uint4 p0 = (uint4){0,0,0,0}, p1 = (uint4){0,0,0,0};
            if (c4 == 0){
                p0.x = pack2(af_reg[0], af_reg[1]); p0.y = pack2(af_reg[2], af_reg[3]);
                p0.z = pack2(af_reg[4], af_reg[5]); p0.w = pack2(af_reg[6], af_reg[7]);
                p1.x = pack2(af_reg[8], af_reg[9]);
            }
            *(uint4*)sAw0 = p0;
            *(uint4*)sAw1 = p1;
            __syncthreads();
            MFMA_STEP()
        }
        // ---- fused passing-MLP epilogue: wave w == head d (r4-verified strides) ----
        __syncthreads();
        unsigned short* sE = (unsigned short*)(smem + w*9216); // [64][72] bf16
#pragma unroll
        for (int mt = 0; mt < 4; ++mt)
#pragma unroll
        for (int nt = 0; nt < 4; ++nt)
#pragma unroll
        for (int rg = 0; rg < 4; ++rg)
            sE[(mt*16 + quad*4 + rg)*72 + nt*16 + l15] = f2bf(acc[mt][nt][rg]);
        __syncthreads();
        f32x4 yacc[4][4];
#pragma unroll
        for (int a = 0; a < 4; ++a)
#pragma unroll
        for (int b = 0; b < 4; ++b) yacc[a][b] = (f32x4){0.f, 0.f, 0.f, 0.f};
#pragma unroll
        for (int kb = 0; kb < 2; ++kb){
            short8 ea[4], wb[4];
#pragma unroll
            for (int mt = 0; mt < 4; ++mt) ea[mt] = *(const short8*)&sE[(mt*16 + l15)*72 + kb*32 + quad*8];
#pragma unroll
            for (int ot = 0; ot < 4; ++ot) wb[ot] = *(const short8*)&sW1[(ot*16 + l15)*72 + kb*32 + quad*8];
#pragma unroll
            for (int mt = 0; mt < 4; ++mt)
#pragma unroll
            for (int ot = 0; ot < 4; ++ot)
                yacc[mt][ot] = __builtin_amdgcn_mfma_f32_16x16x32_bf16(ea[mt], wb[ot], yacc[mt][ot], 0, 0, 0);
        }
        float pb1v[4], w2r[4][3];
#pragma unroll
        for (int ot = 0; ot < 4; ++ot){
            pb1v[ot] = pb1[ot*16 + l15];
#pragma unroll
            for (int j = 0; j < 3; ++j) w2r[ot][j] = pw2[(ot*16 + l15)*3 + j];
        }
#pragma unroll
        for (int mt = 0; mt < 4; ++mt){
            float part[4][3];
#pragma unroll
            for (int rg = 0; rg < 4; ++rg)
#pragma unroll
            for (int j = 0; j < 3; ++j) part[rg][j] = 0.f;
#pragma unroll
            for (int ot = 0; ot < 4; ++ot)
#pragma unroll
            for (int rg = 0; rg < 4; ++rg){
                float yv = fmaxf(yacc[mt][ot][rg] + pb1v[ot], 0.f);
#pragma unroll
                for (int j = 0; j < 3; ++j) part[rg][j] = fmaf(yv, w2r[ot][j], part[rg][j]);
            }
#pragma unroll
            for (int off = 1; off < 16; off <<= 1)
#pragma unroll
            for (int rg = 0; rg < 4; ++rg)
#pragma unroll
            for (int j = 0; j < 3; ++j) part[rg][j] += __shfl_xor(part[rg][j], off, 64);
            if (l15 == 0){
#pragma unroll
                for (int rg = 0; rg < 4; ++rg)
#pragma unroll
                for (int j = 0; j < 3; ++j)
                    p2[(row0 + mt*16 + quad*4 + rg)*12 + w*3 + j] = part[rg][j] + pb2[j];
            }
        }
    } else {
        // ---- stacked usum [4096][704] @ Bt -> emb [4096][256] fp32 ----
        int row0 = (bb - 480) * 64;
        const char* Bb = (const char*)((row0 < RAG) ? Bte : Bta);
        const char* Ub = (const char*)usum;
        int corig = (lane & 7) ^ (lane >> 3);
        size_t aoff = (size_t)(row0 + w*16 + (lane >> 3)) * (KP2*2) + corig*16;
#pragma unroll
        for (int s = 0; s < 11; ++s){
            __syncthreads();
            const char* Bstep = Bb + s*32768;
#pragma unroll
            for (int ii = 0; ii < 8; ++ii)
                gload_lds(Bstep + w*8192 + ii*1024 + lane*16, smem + w*8192 + ii*1024);
            gload_lds(Ub + aoff + s*128,              smem + 32768 + w*2048);
            gload_lds(Ub + aoff + 8*(KP2*2) + s*128,  smem + 32768 + w*2048 + 1024);
            __syncthreads();
            MFMA_STEP()
        }
#pragma unroll
        for (int mt = 0; mt < 4; ++mt)
#pragma unroll
        for (int nt = 0; nt < 4; ++nt)
#pragma unroll
        for (int rg = 0; rg < 4; ++rg)
            emb[(row0 + mt*16 + quad*4 + rg)*256 + w*64 + nt*16 + l15] = acc[mt][nt][rg];
    }
}

// ---------------- K3: merge + GRU (MFMA) + heads, 16 agents per block ----------------
__global__ void __launch_bounds__(256) k_final(
    const float* __restrict__ own, const float* __restrict__ hidden,
    const float* __restrict__ fc1w, const float* __restrict__ fc1b,
    const float* __restrict__ mergw,
    const float* __restrict__ bih, const float* __restrict__ bhh,
    const float* __restrict__ f2b1, const float* __restrict__ f2w2, const float* __restrict__ f2b2,
    const unsigned short* __restrict__ Wgru, const unsigned short* __restrict__ B2,
    const float* __restrict__ emb, const float* __restrict__ p2,
    float* __restrict__ out)
{
    __shared__ __align__(16) unsigned short sA16[16*128];
    __shared__ float sHin[16*65];
    __shared__ float sG[256*17];
    __shared__ float sH2f[16*65];
    __shared__ __align__(16) unsigned short sH2b[16*64];
    __shared__ float sY[16*68];

    int tid = threadIdx.x;
    int w = tid >> 6, lane = tid & 63;
    int l15 = lane & 15, quad = lane >> 4;
    int ag0 = blockIdx.x * 16;

#pragma unroll
    for (int p = 0; p < 4; ++p){
        int idx = tid + p*256;
        int h = idx & 63, a = idx >> 6;
        int ag = ag0 + a;
        float s = fc1b[h];
        const float* ow = own + ag*30;
#pragma unroll
        for (int c = 0; c < 30; ++c) s = fmaf(ow[c], fc1w[c*64 + h], s);
        float m0 = mergw[h], m1 = mergw[64+h], m2 = mergw[128+h], m3 = mergw[192+h];
        float mx = fmaxf(fmaxf(m0, m1), fmaxf(m2, m3));
        float e0 = __expf(m0-mx), e1 = __expf(m1-mx), e2 = __expf(m2-mx), e3 = __expf(m3-mx);
        float inv = 1.f / (e0+e1+e2+e3);
        const float* een = emb + ag*256;
        const float* eal = emb + (RAG + ag)*256;
        float mg = (e0*(een[h]+eal[h]) + e1*(een[64+h]+eal[64+h]) +
                    e2*(een[128+h]+eal[128+h]) + e3*(een[192+h]+eal[192+h])) * inv;
        float x = fmaxf(s + mg, 0.f);
        float hin = hidden[ag*64 + h];
        sA16[a*128 + h]      = f2bf(x);
        sA16[a*128 + 64 + h] = f2bf(hin);
        sHin[a*65 + h] = hin;
    }
    __syncthreads();
    {
        f32x4 g_[4];
#pragma unroll
        for (int t = 0; t < 4; ++t) g_[t] = (f32x4){0.f,0.f,0.f,0.f};
#pragma unroll
        for (int ks = 0; ks < 4; ++ks){
            int kt = ks*32;
            short8 a8 = *(const short8*)&sA16[l15*128 + kt + quad*8];
#pragma unroll
            for (int t = 0; t < 4; ++t){
                int col = (w*4 + t)*16 + l15;
                short8 b8 = *(const short8*)&Wgru[col*128 + kt + quad*8];
                g_[t] = __builtin_amdgcn_mfma_f32_16x16x32_bf16(a8, b8, g_[t], 0, 0, 0);
            }
        }
#pragma unroll
        for (int t = 0; t < 4; ++t){
            int col = (w*4 + t)*16 + l15;
#pragma unroll
            for (int rg = 0; rg < 4; ++rg) sG[col*17 + quad*4 + rg] = g_[t][rg];
        }
    }
    __syncthreads();
#pragma unroll
    for (int p = 0; p < 4; ++p){
        int idx = tid + p*256;
        int a = idx & 15, h = idx >> 4;
        float rs  = sG[h*17 + a]        + bih[h]      + bhh[h];
        float zs  = sG[(64+h)*17 + a]   + bih[64+h]   + bhh[64+h];
        float in_ = sG[(128+h)*17 + a]  + bih[128+h];
        float hn  = sG[(192+h)*17 + a]  + bhh[128+h];
        float r = 1.f / (1.f + __expf(-rs));
        float z = 1.f / (1.f + __expf(-zs));
        float n = tanhf(in_ + r*hn);
        float hv = (1.f - z)*n + z*sHin[a*65 + h];
        sH2f[a*65 + h] = hv;
        sH2b[a*64 + h] = f2bf(hv);
    }
    __syncthreads();
    {
        f32x4 y = (f32x4){0.f,0.f,0.f,0.f};
#pragma unroll
        for (int ks = 0; ks < 2; ++ks){
            int kt = ks*32;
            short8 a8 = *(const short8*)&sH2b[l15*64 + kt + quad*8];
            short8 b8 = *(const short8*)&B2[(w*16 + l15)*64 + kt + quad*8];
            y = __builtin_amdgcn_mfma_f32_16x16x32_bf16(a8, b8, y, 0, 0, 0);
        }
        float b1v = f2b1[w*16 + l15];
#pragma unroll
        for (int rg = 0; rg < 4; ++rg)
            sY[(quad*4 + rg)*68 + w*16 + l15] = fmaxf(y[rg] + b1v, 0.f);
    }
    __syncthreads();
    for (int idx = tid; idx < 16*19; idx += 256){
        int a = idx / 19, j = idx - a*19;
        float s2 = f2b2[j];
        for (int c = 0; c < 64; ++c) s2 = fmaf(sY[a*68 + c], f2w2[c*19 + j], s2);
        out[(ag0 + a)*22 + ((j < 9) ? j : j + 3)] = s2;
    }
    if (tid < 48){
        int a = tid / 3, j = tid - a*3;
        float best = -1e30f;
        const float* pp = p2 + (ag0 + a)*180;
        for (int l = 0; l < 15; ++l){
            float mean = 0.25f*(pp[l*12 + j] + pp[l*12 + 3 + j] + pp[l*12 + 6 + j] + pp[l*12 + 9 + j]);
            best = fmaxf(best, mean);
        }
        out[(ag0 + a)*22 + 9 + j] = best;
    }
#pragma unroll
    for (int p = 0; p < 4; ++p){
        int idx = tid + p*256;
        int h = idx & 63, a = idx >> 6;
        out[QOFF + (ag0 + a)*64 + h] = sH2f[a*65 + h];
    }
}

extern "C" void kernel_launch(void* const* d_in, const int* in_sizes, int n_in,
                              void* d_out, int out_size, void* d_ws, size_t ws_size,
                              hipStream_t stream) {
    const float* own    = (const float*)d_in[1];
    const float* allyf  = (const float*)d_in[2];
    const float* enemyf = (const float*)d_in[3];
    const float* hidden = (const float*)d_in[4];
    const float* fc1w   = (const float*)d_in[5];
    const float* fc1b   = (const float*)d_in[6];
    const float* hew1   = (const float*)d_in[7];
    const float* heb1   = (const float*)d_in[8];
    const float* hew2   = (const float*)d_in[9];
    const float* heb2   = (const float*)d_in[10];
    const float* haw1   = (const float*)d_in[11];
    const float* hab1   = (const float*)d_in[12];
    const float* haw2   = (const float*)d_in[13];
    const float* hab2   = (const float*)d_in[14];
    const float* mergw  = (const float*)d_in[15];
    const float* wih    = (const float*)d_in[16];
    const float* whh    = (const float*)d_in[17];
    const float* bih    = (const float*)d_in[18];
    const float* bhh    = (const float*)d_in[19];
    const float* f2w1   = (const float*)d_in[20];
    const float* f2b1   = (const float*)d_in[21];
    const float* f2w2   = (const float*)d_in[22];
    const float* f2b2   = (const float*)d_in[23];
    const float* pw1    = (const float*)d_in[24];
    const float* pb1    = (const float*)d_in[25];
    const float* pw2    = (const float*)d_in[26];
    const float* pb2    = (const float*)d_in[27];
    float* out = (float*)d_out;

    char* W = (char*)d_ws;
    unsigned short* Bte  = (unsigned short*)(W + 0);         // 11*16384*2 = 360448 (LDS-image)
    unsigned short* Bta  = (unsigned short*)(W + 360448);    // 360448
    unsigned short* usum = (unsigned short*)(W + 720896);    // 4096*704*2 = 5767168
    float*          emb  = (float*)(W + 6488064);            // 4096*256*4 = 4194304
    float*          p2   = (float*)(W + 10682368);           // 30720*12*4 = 1474560
    unsigned short* ha1  = (unsigned short*)(W + 12156928);  // 30720*64*2 = 3932160
    unsigned short* Wgru = (unsigned short*)(W + 16089088);  // 256*128*2  = 65536
    unsigned short* B2   = (unsigned short*)(W + 16154624);  // 64*64*2    = 8192

    k_usum<<<RAG + 23, 256, 0, stream>>>(enemyf, hew1, heb1, allyf, haw1, hab1,
                                         hew2, heb2, haw2, hab2, wih, whh, f2w1,
                                         Bte, Bta, Wgru, B2, ha1, usum);
    k_gemm<<<544, 256, 0, stream>>>(Bte, Bta, ha1, allyf, usum,
                                    pw1, pb1, pw2, pb2, emb, p2);
    k_final<<<RAG/16, 256, 0, stream>>>(own, hidden, fc1w, fc1b, mergw,
                                        bih, bhh, f2b1, f2w2, f2b2,
                                        Wgru, B2, emb, p2, out);
}

// Round 7
// 187.295 us; speedup vs baseline: 1.4572x; 1.1972x over previous
//
#include <hip/hip_runtime.h>
#include <hip/hip_bf16.h>

#define RAG   2048          // BS*NA
#define KP2   704           // padded K: k' = i*64+h (i<10), aug 640..649, zero 650..703
#define QOFF  45056         // 128*16*22

typedef __attribute__((ext_vector_type(8))) short short8;
typedef __attribute__((ext_vector_type(4))) float f32x4;

__device__ inline unsigned short f2bf(float f){
    unsigned u = __float_as_uint(f);
    u += 0x7fffu + ((u >> 16) & 1u);            // RNE
    return (unsigned short)(u >> 16);
}
__device__ inline unsigned pack2(float a, float b){
    return (unsigned)f2bf(a) | ((unsigned)f2bf(b) << 16);
}
__device__ inline void gload_lds(const void* g, void* l){
    __builtin_amdgcn_global_load_lds(
        (const __attribute__((address_space(1))) void*)g,
        (__attribute__((address_space(3))) void*)l, 16, 0, 0);
}

// ---------------- K1: blocks 0..2047 = per-agent Usum rows (enemy + ally) + ha1;
// blocks 2048..2069 = B prepack (LDS-image swizzled); 2070..2085 Wgru; 2086..2087 B2. ----------------
__global__ void __launch_bounds__(256) k_usum(
    const float* __restrict__ ef, const float* __restrict__ hew1, const float* __restrict__ heb1,
    const float* __restrict__ af, const float* __restrict__ haw1, const float* __restrict__ hab1,
    const float* __restrict__ hew2, const float* __restrict__ heb2,
    const float* __restrict__ haw2, const float* __restrict__ hab2,
    const float* __restrict__ wih, const float* __restrict__ whh, const float* __restrict__ f2w1,
    unsigned short* __restrict__ Bte, unsigned short* __restrict__ Bta,
    unsigned short* __restrict__ Wgru, unsigned short* __restrict__ B2,
    unsigned short* __restrict__ ha1, unsigned short* __restrict__ usum)
{
    int bb = blockIdx.x, tid = threadIdx.x;
    if (bb >= RAG){
        int p = bb - RAG;
        if (p < 22){
            int mat = p & 1;                 // 0 = enemy, 1 = ally
            int s   = p >> 1;                // step 0..10
            const float* w2 = mat ? haw2 : hew2;
            const float* b2 = mat ? hab2 : heb2;
            int ld = mat ? 2560 : 2820;
            unsigned short* Bt = mat ? Bta : Bte;
            int n = tid, n7 = n & 7;
            unsigned pk[32];
#pragma unroll
            for (int u2 = 0; u2 < 32; ++u2){
                int cst = u2 >> 2;                   // stored chunk 0..7
                int co  = cst ^ n7;                  // original chunk
                int j0  = (u2 * 2) & 7;
                int k0 = s*64 + co*8 + j0, k1 = k0 + 1;
                float v0 = 0.f, v1 = 0.f;
                if (k0 < 640)      v0 = w2[(k0 & 63)*ld + (k0 >> 6)*256 + n];
                else if (k0 < 650) v0 = b2[(k0 - 640)*256 + n];
                if (k1 < 640)      v1 = w2[(k1 & 63)*ld + (k1 >> 6)*256 + n];
                else if (k1 < 650) v1 = b2[(k1 - 640)*256 + n];
                pk[u2] = pack2(v0, v1);
            }
            uint4* dst = (uint4*)&Bt[s*16384 + n*64];
#pragma unroll
            for (int q = 0; q < 8; ++q)
                dst[q] = (uint4){pk[q*4], pk[q*4+1], pk[q*4+2], pk[q*4+3]};
        } else if (p < 38){
            // Wgru prepack spread across 16 blocks x 8 elems/thread (coalesced)
            int base = (p - 22) * 2048;
#pragma unroll
            for (int i = 0; i < 8; ++i){
                int it = base + i*256 + tid;
                int n = it >> 7, k = it & 127;
                float v;
                if (n < 128)      v = (k < 64) ? wih[n*64 + k] : whh[n*64 + k - 64];
                else if (n < 192) v = (k < 64) ? wih[n*64 + k] : 0.f;
                else              v = (k < 64) ? 0.f : whh[(n-64)*64 + k - 64];
                Wgru[it] = f2bf(v);
            }
        } else {
            // B2 prepack: 2 blocks x 8 elems/thread
            int base = (p - 38) * 2048;
#pragma unroll
            for (int i = 0; i < 8; ++i){
                int it = base + i*256 + tid;
                int n = it >> 6, k = it & 63;
                B2[it] = f2bf(f2w1[k*64 + n]);
            }
        }
        return;
    }
    __shared__ float s_ef[16][10], s_af[15][10];
    __shared__ float s_he[16][64], s_ha[15][64];
    int ag = bb;
    if (tid < 160) s_ef[tid/10][tid%10] = ef[ag*160 + tid];
    if (tid < 150) s_af[tid/10][tid%10] = af[ag*150 + tid];
    __syncthreads();
    for (int idx = tid; idx < 16*64; idx += 256){
        int en = idx >> 6, h = idx & 63;
        float s = heb1[h];
#pragma unroll
        for (int i = 0; i < 10; ++i) s = fmaf(s_ef[en][i], hew1[i*64 + h], s);
        s_he[en][h] = fmaxf(s, 0.f);
    }
    for (int idx = tid; idx < 15*64; idx += 256){
        int l = idx >> 6, h = idx & 63;
        float s = hab1[h];
#pragma unroll
        for (int i = 0; i < 10; ++i) s = fmaf(s_af[l][i], haw1[i*64 + h], s);
        s_ha[l][h] = fmaxf(s, 0.f);
    }
    __syncthreads();
    for (int idx = tid; idx < 15*64; idx += 256){
        int l = idx >> 6, h = idx & 63;
        ha1[(ag*15 + l)*64 + h] = f2bf(s_ha[l][h]);
    }
    for (int k = tid; k < KP2; k += 256){
        float ue = 0.f, ua = 0.f;
        if (k < 640){
            int i = k >> 6, h = k & 63;
#pragma unroll
            for (int en = 0; en < 16; ++en) ue = fmaf(s_he[en][h], s_ef[en][i], ue);
#pragma unroll
            for (int l = 0; l < 15; ++l) ua = fmaf(s_ha[l][h], s_af[l][i], ua);
        } else if (k < 650){
            int i = k - 640;
#pragma unroll
            for (int en = 0; en < 16; ++en) ue += s_ef[en][i];
#pragma unroll
            for (int l = 0; l < 15; ++l) ua += s_af[l][i];
        }
        usum[ag*KP2 + k]         = f2bf(ue);
        usum[(RAG + ag)*KP2 + k] = f2bf(ua);
    }
}

// One MFMA K-step (BK=64), fragments from XOR-swizzled LDS (conflict-free).
#define MFMA_STEP()                                                              \
    _Pragma("unroll")                                                            \
    for (int kk = 0; kk < 2; ++kk){                                              \
        int ch = ((kk*4 + quad) ^ l7) * 8;                                       \
        short8 a_[4], b_[4];                                                     \
        _Pragma("unroll")                                                        \
        for (int mt = 0; mt < 4; ++mt) a_[mt] = *(const short8*)&sA[(mt*16 + l15)*64 + ch]; \
        _Pragma("unroll")                                                        \
        for (int nt = 0; nt < 4; ++nt) b_[nt] = *(const short8*)&sB[(w*64 + nt*16 + l15)*64 + ch]; \
        _Pragma("unroll")                                                        \
        for (int mt = 0; mt < 4; ++mt)                                           \
        _Pragma("unroll")                                                        \
        for (int nt = 0; nt < 4; ++nt)                                           \
            acc[mt][nt] = __builtin_amdgcn_mfma_f32_16x16x32_bf16(a_[mt], b_[nt], acc[mt][nt], 0, 0, 0); \
    }

// ---------------- K2: MFMA GEMMs. blocks 0..479: ally rows (A on-the-fly, passing-MLP
// epilogue). blocks 480..543: stacked usum tiles -> emb (A via global_load_lds). ----------------
__global__ void __launch_bounds__(256, 2) k_gemm(
    const unsigned short* __restrict__ Bte, const unsigned short* __restrict__ Bta,
    const unsigned short* __restrict__ ha1, const float* __restrict__ af,
    const unsigned short* __restrict__ usum,
    const float* __restrict__ pw1, const float* __restrict__ pb1,
    const float* __restrict__ pw2, const float* __restrict__ pb2,
    float* __restrict__ emb, float* __restrict__ p2)
{
    __shared__ __align__(16) char smem[50176];
    unsigned short* sB  = (unsigned short*)smem;            // 256 cols x 64 ushorts, swizzled (32KB)
    unsigned short* sA  = (unsigned short*)(smem + 32768);  // 64 rows x 64 ushorts, swizzled (8KB)
    unsigned short* sW1 = (unsigned short*)(smem + 40960);  // [64][72] pw1^T (9216B)

    int tid = threadIdx.x;
    int w = tid >> 6, lane = tid & 63;
    int l15 = lane & 15, quad = lane >> 4, l7 = l15 & 7;
    int bb = blockIdx.x;

    f32x4 acc[4][4];
#pragma unroll
    for (int a = 0; a < 4; ++a)
#pragma unroll
    for (int b = 0; b < 4; ++b) acc[a][b] = (f32x4){0.f, 0.f, 0.f, 0.f};

    if (bb < 480){
        int row0 = bb * 64;
        int r = tid >> 2, c4 = tid & 3, r7 = r & 7;
#pragma unroll
        for (int p = 0; p < 16; ++p){
            int idx = tid + p*256;
            sW1[(idx & 63)*72 + (idx >> 6)] = f2bf(pw1[idx]);
        }
        float af_reg[10];
        {
            const float* ap = af + (row0 + r)*10;
#pragma unroll
            for (int i = 0; i < 10; ++i) af_reg[i] = ap[i];
        }
        float h1f[16];
        {
            const unsigned short* hp = ha1 + (size_t)(row0 + r)*64 + c4*16;
            uint4 ra = *(const uint4*)hp;
            uint4 rb = *(const uint4*)(hp + 8);
            unsigned va[4] = {ra.x, ra.y, ra.z, ra.w};
            unsigned vb[4] = {rb.x, rb.y, rb.z, rb.w};
#pragma unroll
            for (int q = 0; q < 4; ++q){
                h1f[q*2+0]   = __uint_as_float(va[q] << 16);
                h1f[q*2+1]   = __uint_as_float(va[q] & 0xffff0000u);
                h1f[8+q*2+0] = __uint_as_float(vb[q] << 16);
                h1f[8+q*2+1] = __uint_as_float(vb[q] & 0xffff0000u);
            }
        }
        unsigned short* sAw0 = &sA[r*64 + (((2*c4)     ^ r7) * 8)];
        unsigned short* sAw1 = &sA[r*64 + (((2*c4 + 1) ^ r7) * 8)];
        const char* Bb = (const char*)Bta;
#pragma unroll
        for (int s = 0; s < 10; ++s){
            __syncthreads();
            const char* Bstep = Bb + s*32768;
#pragma unroll
            for (int ii = 0; ii < 8; ++ii)
                gload_lds(Bstep + w*8192 + ii*1024 + lane*16, smem + w*8192 + ii*1024);
            float avf = af_reg[s];
            uint4 p0, p1;
            p0.x = pack2(h1f[0]*avf,  h1f[1]*avf);  p0.y = pack2(h1f[2]*avf,  h1f[3]*avf);
            p0.z = pack2(h1f[4]*avf,  h1f[5]*avf);  p0.w = pack2(h1f[6]*avf,  h1f[7]*avf);
            p1.x = pack2(h1f[8]*avf,  h1f[9]*avf);  p1.y = pack2(h1f[10]*avf, h1f[11]*avf);
            p1.z = pack2(h1f[12]*avf, h1f[13]*avf); p1.w = pack2(h1f[14]*avf, h1f[15]*avf);
            *(uint4*)sAw0 = p0;
            *(uint4*)sAw1 = p1;
            __syncthreads();
            MFMA_STEP()
        }
        {   // tail step s=10: k 640..649 = af[i], rest zero
            __syncthreads();
            const char* Bstep = Bb + 10*32768;
#pragma unroll
            for (int ii = 0; ii < 8; ++ii)
                gload_lds(Bstep + w*8192 + ii*1024 + lane*16, smem + w*8192 + ii*1024);
            uint4 p0 = (uint4){0,0,0,0}, p1 = (uint4){0,0,0,0};
            if (c4 == 0){
                p0.x = pack2(af_reg[0], af_reg[1]); p0.y = pack2(af_reg[2], af_reg[3]);
                p0.z = pack2(af_reg[4], af_reg[5]); p0.w = pack2(af_reg[6], af_reg[7]);
                p1.x = pack2(af_reg[8], af_reg[9]);
            }
            *(uint4*)sAw0 = p0;
            *(uint4*)sAw1 = p1;
            __syncthreads();
            MFMA_STEP()
        }
        // ---- fused passing-MLP epilogue: wave w == head d ----
        __syncthreads();
        unsigned short* sE = (unsigned short*)(smem + w*9216); // [64][72] bf16
#pragma unroll
        for (int mt = 0; mt < 4; ++mt)
#pragma unroll
        for (int nt = 0; nt < 4; ++nt)
#pragma unroll
        for (int rg = 0; rg < 4; ++rg)
            sE[(mt*16 + quad*4 + rg)*72 + nt*16 + l15] = f2bf(acc[mt][nt][rg]);
        __syncthreads();
        f32x4 yacc[4][4];
#pragma unroll
        for (int a = 0; a < 4; ++a)
#pragma unroll
        for (int b = 0; b < 4; ++b) yacc[a][b] = (f32x4){0.f, 0.f, 0.f, 0.f};
#pragma unroll
        for (int kb = 0; kb < 2; ++kb){
            short8 ea[4], wb[4];
#pragma unroll
            for (int mt = 0; mt < 4; ++mt) ea[mt] = *(const short8*)&sE[(mt*16 + l15)*72 + kb*32 + quad*8];
#pragma unroll
            for (int ot = 0; ot < 4; ++ot) wb[ot] = *(const short8*)&sW1[(ot*16 + l15)*72 + kb*32 + quad*8];
#pragma unroll
            for (int mt = 0; mt < 4; ++mt)
#pragma unroll
            for (int ot = 0; ot < 4; ++ot)
                yacc[mt][ot] = __builtin_amdgcn_mfma_f32_16x16x32_bf16(ea[mt], wb[ot], yacc[mt][ot], 0, 0, 0);
        }
        float pb1v[4], w2r[4][3];
#pragma unroll
        for (int ot = 0; ot < 4; ++ot){
            pb1v[ot] = pb1[ot*16 + l15];
#pragma unroll
            for (int j = 0; j < 3; ++j) w2r[ot][j] = pw2[(ot*16 + l15)*3 + j];
        }
#pragma unroll
        for (int mt = 0; mt < 4; ++mt){
            float part[4][3];
#pragma unroll
            for (int rg = 0; rg < 4; ++rg)
#pragma unroll
            for (int j = 0; j < 3; ++j) part[rg][j] = 0.f;
#pragma unroll
            for (int ot = 0; ot < 4; ++ot)
#pragma unroll
            for (int rg = 0; rg < 4; ++rg){
                float yv = fmaxf(yacc[mt][ot][rg] + pb1v[ot], 0.f);
#pragma unroll
                for (int j = 0; j < 3; ++j) part[rg][j] = fmaf(yv, w2r[ot][j], part[rg][j]);
            }
#pragma unroll
            for (int off = 1; off < 16; off <<= 1)
#pragma unroll
            for (int rg = 0; rg < 4; ++rg)
#pragma unroll
            for (int j = 0; j < 3; ++j) part[rg][j] += __shfl_xor(part[rg][j], off, 64);
            if (l15 == 0){
#pragma unroll
                for (int rg = 0; rg < 4; ++rg)
#pragma unroll
                for (int j = 0; j < 3; ++j)
                    p2[(row0 + mt*16 + quad*4 + rg)*12 + w*3 + j] = part[rg][j] + pb2[j];
            }
        }
    } else {
        // ---- stacked usum [4096][704] @ Bt -> emb [4096][256] fp32 ----
        int row0 = (bb - 480) * 64;
        const char* Bb = (const char*)((row0 < RAG) ? Bte : Bta);
        const char* Ub = (const char*)usum;
        int corig = (lane & 7) ^ (lane >> 3);
        size_t aoff = (size_t)(row0 + w*16 + (lane >> 3)) * (KP2*2) + corig*16;
#pragma unroll
        for (int s = 0; s < 11; ++s){
            __syncthreads();
            const char* Bstep = Bb + s*32768;
#pragma unroll
            for (int ii = 0; ii < 8; ++ii)
                gload_lds(Bstep + w*8192 + ii*1024 + lane*16, smem + w*8192 + ii*1024);
            gload_lds(Ub + aoff + s*128,              smem + 32768 + w*2048);
            gload_lds(Ub + aoff + 8*(KP2*2) + s*128,  smem + 32768 + w*2048 + 1024);
            __syncthreads();
            MFMA_STEP()
        }
#pragma unroll
        for (int mt = 0; mt < 4; ++mt)
#pragma unroll
        for (int nt = 0; nt < 4; ++nt)
#pragma unroll
        for (int rg = 0; rg < 4; ++rg)
            emb[(row0 + mt*16 + quad*4 + rg)*256 + w*64 + nt*16 + l15] = acc[mt][nt][rg];
    }
}

// ---------------- K3: merge + GRU (MFMA) + heads, 16 agents per block ----------------
__global__ void __launch_bounds__(256) k_final(
    const float* __restrict__ own, const float* __restrict__ hidden,
    const float* __restrict__ fc1w, const float* __restrict__ fc1b,
    const float* __restrict__ mergw,
    const float* __restrict__ bih, const float* __restrict__ bhh,
    const float* __restrict__ f2b1, const float* __restrict__ f2w2, const float* __restrict__ f2b2,
    const unsigned short* __restrict__ Wgru, const unsigned short* __restrict__ B2,
    const float* __restrict__ emb, const float* __restrict__ p2,
    float* __restrict__ out)
{
    __shared__ __align__(16) unsigned short sA16[16*128];
    __shared__ float sHin[16*65];
    __shared__ float sG[256*17];
    __shared__ float sH2f[16*65];
    __shared__ __align__(16) unsigned short sH2b[16*64];
    __shared__ float sY[16*68];

    int tid = threadIdx.x;
    int w = tid >> 6, lane = tid & 63;
    int l15 = lane & 15, quad = lane >> 4;
    int ag0 = blockIdx.x * 16;

#pragma unroll
    for (int p = 0; p < 4; ++p){
        int idx = tid + p*256;
        int h = idx & 63, a = idx >> 6;
        int ag = ag0 + a;
        float s = fc1b[h];
        const float* ow = own + ag*30;
#pragma unroll
        for (int c = 0; c < 30; ++c) s = fmaf(ow[c], fc1w[c*64 + h], s);
        float m0 = mergw[h], m1 = mergw[64+h], m2 = mergw[128+h], m3 = mergw[192+h];
        float mx = fmaxf(fmaxf(m0, m1), fmaxf(m2, m3));
        float e0 = __expf(m0-mx), e1 = __expf(m1-mx), e2 = __expf(m2-mx), e3 = __expf(m3-mx);
        float inv = 1.f / (e0+e1+e2+e3);
        const float* een = emb + ag*256;
        const float* eal = emb + (RAG + ag)*256;
        float mg = (e0*(een[h]+eal[h]) + e1*(een[64+h]+eal[64+h]) +
                    e2*(een[128+h]+eal[128+h]) + e3*(een[192+h]+eal[192+h])) * inv;
        float x = fmaxf(s + mg, 0.f);
        float hin = hidden[ag*64 + h];
        sA16[a*128 + h]      = f2bf(x);
        sA16[a*128 + 64 + h] = f2bf(hin);
        sHin[a*65 + h] = hin;
    }
    __syncthreads();
    {
        f32x4 g_[4];
#pragma unroll
        for (int t = 0; t < 4; ++t) g_[t] = (f32x4){0.f,0.f,0.f,0.f};
#pragma unroll
        for (int ks = 0; ks < 4; ++ks){
            int kt = ks*32;
            short8 a8 = *(const short8*)&sA16[l15*128 + kt + quad*8];
#pragma unroll
            for (int t = 0; t < 4; ++t){
                int col = (w*4 + t)*16 + l15;
                short8 b8 = *(const short8*)&Wgru[col*128 + kt + quad*8];
                g_[t] = __builtin_amdgcn_mfma_f32_16x16x32_bf16(a8, b8, g_[t], 0, 0, 0);
            }
        }
#pragma unroll
        for (int t = 0; t < 4; ++t){
            int col = (w*4 + t)*16 + l15;
#pragma unroll
            for (int rg = 0; rg < 4; ++rg) sG[col*17 + quad*4 + rg] = g_[t][rg];
        }
    }
    __syncthreads();
#pragma unroll
    for (int p = 0; p < 4; ++p){
        int idx = tid + p*256;
        int a = idx & 15, h = idx >> 4;
        float rs  = sG[h*17 + a]        + bih[h]      + bhh[h];
        float zs  = sG[(64+h)*17 + a]   + bih[64+h]   + bhh[64+h];
        float in_ = sG[(128+h)*17 + a]  + bih[128+h];
        float hn  = sG[(192+h)*17 + a]  + bhh[128+h];
        float r = 1.f / (1.f + __expf(-rs));
        float z = 1.f / (1.f + __expf(-zs));
        float n = tanhf(in_ + r*hn);
        float hv = (1.f - z)*n + z*sHin[a*65 + h];
        sH2f[a*65 + h] = hv;
        sH2b[a*64 + h] = f2bf(hv);
    }
    __syncthreads();
    {
        f32x4 y = (f32x4){0.f,0.f,0.f,0.f};
#pragma unroll
        for (int ks = 0; ks < 2; ++ks){
            int kt = ks*32;
            short8 a8 = *(const short8*)&sH2b[l15*64 + kt + quad*8];
            short8 b8 = *(const short8*)&B2[(w*16 + l15)*64 + kt + quad*8];
            y = __builtin_amdgcn_mfma_f32_16x16x32_bf16(a8, b8, y, 0, 0, 0);
        }
        float b1v = f2b1[w*16 + l15];
#pragma unroll
        for (int rg = 0; rg < 4; ++rg)
            sY[(quad*4 + rg)*68 + w*16 + l15] = fmaxf(y[rg] + b1v, 0.f);
    }
    __syncthreads();
    for (int idx = tid; idx < 16*19; idx += 256){
        int a = idx / 19, j = idx - a*19;
        float s2 = f2b2[j];
        for (int c = 0; c < 64; ++c) s2 = fmaf(sY[a*68 + c], f2w2[c*19 + j], s2);
        out[(ag0 + a)*22 + ((j < 9) ? j : j + 3)] = s2;
    }
    if (tid < 48){
        int a = tid / 3, j = tid - a*3;
        float best = -1e30f;
        const float* pp = p2 + (ag0 + a)*180;
        for (int l = 0; l < 15; ++l){
            float mean = 0.25f*(pp[l*12 + j] + pp[l*12 + 3 + j] + pp[l*12 + 6 + j] + pp[l*12 + 9 + j]);
            best = fmaxf(best, mean);
        }
        out[(ag0 + a)*22 + 9 + j] = best;
    }
#pragma unroll
    for (int p = 0; p < 4; ++p){
        int idx = tid + p*256;
        int h = idx & 63, a = idx >> 6;
        out[QOFF + (ag0 + a)*64 + h] = sH2f[a*65 + h];
    }
}

extern "C" void kernel_launch(void* const* d_in, const int* in_sizes, int n_in,
                              void* d_out, int out_size, void* d_ws, size_t ws_size,
                              hipStream_t stream) {
    const float* own    = (const float*)d_in[1];
    const float* allyf  = (const float*)d_in[2];
    const float* enemyf = (const float*)d_in[3];
    const float* hidden = (const float*)d_in[4];
    const float* fc1w   = (const float*)d_in[5];
    const float* fc1b   = (const float*)d_in[6];
    const float* hew1   = (const float*)d_in[7];
    const float* heb1   = (const float*)d_in[8];
    const float* hew2   = (const float*)d_in[9];
    const float* heb2   = (const float*)d_in[10];
    const float* haw1   = (const float*)d_in[11];
    const float* hab1   = (const float*)d_in[12];
    const float* haw2   = (const float*)d_in[13];
    const float* hab2   = (const float*)d_in[14];
    const float* mergw  = (const float*)d_in[15];
    const float* wih    = (const float*)d_in[16];
    const float* whh    = (const float*)d_in[17];
    const float* bih    = (const float*)d_in[18];
    const float* bhh    = (const float*)d_in[19];
    const float* f2w1   = (const float*)d_in[20];
    const float* f2b1   = (const float*)d_in[21];
    const float* f2w2   = (const float*)d_in[22];
    const float* f2b2   = (const float*)d_in[23];
    const float* pw1    = (const float*)d_in[24];
    const float* pb1    = (const float*)d_in[25];
    const float* pw2    = (const float*)d_in[26];
    const float* pb2    = (const float*)d_in[27];
    float* out = (float*)d_out;

    char* W = (char*)d_ws;
    unsigned short* Bte  = (unsigned short*)(W + 0);         // 11*16384*2 = 360448 (LDS-image)
    unsigned short* Bta  = (unsigned short*)(W + 360448);    // 360448
    unsigned short* usum = (unsigned short*)(W + 720896);    // 4096*704*2 = 5767168
    float*          emb  = (float*)(W + 6488064);            // 4096*256*4 = 4194304
    float*          p2   = (float*)(W + 10682368);           // 30720*12*4 = 1474560
    unsigned short* ha1  = (unsigned short*)(W + 12156928);  // 30720*64*2 = 3932160
    unsigned short* Wgru = (unsigned short*)(W + 16089088);  // 256*128*2  = 65536
    unsigned short* B2   = (unsigned short*)(W + 16154624);  // 64*64*2    = 8192

    k_usum<<<RAG + 40, 256, 0, stream>>>(enemyf, hew1, heb1, allyf, haw1, hab1,
                                         hew2, heb2, haw2, hab2, wih, whh, f2w1,
                                         Bte, Bta, Wgru, B2, ha1, usum);
    k_gemm<<<544, 256, 0, stream>>>(Bte, Bta, ha1, allyf, usum,
                                    pw1, pb1, pw2, pb2, emb, p2);
    k_final<<<RAG/16, 256, 0, stream>>>(own, hidden, fc1w, fc1b, mergw,
                                        bih, bhh, f2b1, f2w2, f2b2,
                                        Wgru, B2, emb, p2, out);
}